// Round 1
// 474.765 us; speedup vs baseline: 1.5604x; 1.5604x over previous
//
#include <hip/hip_runtime.h>

#define CS 128   // chunk size
#define DH 64    // head dim
#define DS 128   // state dim
#define NC 32    // num chunks
#define NBH 64   // B*H
#define SEQ 4096

typedef __attribute__((ext_vector_type(8))) short short8;
typedef __attribute__((ext_vector_type(4))) short short4v;
typedef __attribute__((ext_vector_type(4))) float f32x4;

// split fp32 into bf16 hi (truncate) + bf16 lo (truncate of remainder).
// missing mass ~2^-16 relative -> fp32-class accuracy with 3 MFMAs.
__device__ __forceinline__ void bsplit(float x, short &h, short &l) {
  unsigned u = __float_as_uint(x);
  h = (short)(unsigned short)(u >> 16);
  float r = x - __uint_as_float(u & 0xffff0000u);
  l = (short)(unsigned short)(__float_as_uint(r) >> 16);
}

__device__ __forceinline__ void split4(float4 v, short4v &h, short4v &l) {
  short h0,h1,h2,h3,l0,l1,l2,l3;
  bsplit(v.x,h0,l0); bsplit(v.y,h1,l1); bsplit(v.z,h2,l2); bsplit(v.w,h3,l3);
  h = (short4v){h0,h1,h2,h3};
  l = (short4v){l0,l1,l2,l3};
}

// ---------------- Phase 1: hT[d][s] = sum_t X[t][d] * dte[t] * B[t][s]  (MFMA bf16x3) ----------------
__global__ __launch_bounds__(256, 4) void p1_hcontrib(
    const float* __restrict__ A, const float* __restrict__ X,
    const float* __restrict__ B, float* __restrict__ hbuf,
    float* __restrict__ dtot)
{
  __shared__ float csum[CS];
  __shared__ float Xs[32][65];    // fp32 staged, pad 65 -> ~2-way banks on strided reads
  __shared__ float Bs[32][129];   // fp32 staged, pad 129

  const int blk = blockIdx.x;
  const int bh  = blk >> 5;
  const int c   = blk & 31;
  const int tid = threadIdx.x;
  const int lane = tid & 63, w = tid >> 6;
  const int g4 = lane >> 4, l15 = lane & 15;

  const float* Ac = A + bh * SEQ + c * CS;
  const float* Xc = X + (size_t)(bh * SEQ + c * CS) * DH;
  const float* Bc = B + (size_t)(bh * SEQ + c * CS) * DS;
  float* hout = hbuf + (size_t)blk * DS * DH;   // transposed: [DH][DS]

  if (tid < CS) csum[tid] = Ac[tid];
  __syncthreads();
  for (int off = 1; off < CS; off <<= 1) {
    float v = 0.f;
    if (tid < CS) { v = csum[tid]; if (tid >= off) v += csum[tid - off]; }
    __syncthreads();
    if (tid < CS) csum[tid] = v;
    __syncthreads();
  }
  const float cl = csum[CS - 1];
  if (tid == 0) dtot[blk] = __expf(cl);

  f32x4 acc[4][2];   // [mt over d][ntl over this wave's 32 s-cols]
#pragma unroll
  for (int mt = 0; mt < 4; ++mt)
#pragma unroll
    for (int n = 0; n < 2; ++n) acc[mt][n] = (f32x4){0.f,0.f,0.f,0.f};

  for (int kt = 0; kt < 4; ++kt) {
    const int t0 = kt * 32;
#pragma unroll
    for (int m = 0; m < 2; ++m) {
      int q = m * 256 + tid; int r = q >> 4, c4 = q & 15;
      float4 v = *(const float4*)(Xc + (size_t)(t0 + r) * DH + c4 * 4);
      Xs[r][c4*4+0] = v.x; Xs[r][c4*4+1] = v.y; Xs[r][c4*4+2] = v.z; Xs[r][c4*4+3] = v.w;
    }
#pragma unroll
    for (int m = 0; m < 4; ++m) {
      int q = m * 256 + tid; int r = q >> 5, c4 = q & 31;
      float4 v = *(const float4*)(Bc + (size_t)(t0 + r) * DS + c4 * 4);
      Bs[r][c4*4+0] = v.x; Bs[r][c4*4+1] = v.y; Bs[r][c4*4+2] = v.z; Bs[r][c4*4+3] = v.w;
    }
    __syncthreads();

    float dte[8];
#pragma unroll
    for (int j = 0; j < 8; ++j) dte[j] = __expf(cl - csum[t0 + g4 * 8 + j]);

    // A-frags: X^T rows = d, k = t (strided fp32 reads, split in reg)
    short8 xh[4], xl[4];
#pragma unroll
    for (int mt = 0; mt < 4; ++mt)
#pragma unroll
      for (int j = 0; j < 8; ++j) {
        short h, l; bsplit(Xs[g4 * 8 + j][mt * 16 + l15], h, l);
        xh[mt][j] = h; xl[mt][j] = l;
      }
#pragma unroll
    for (int ntl = 0; ntl < 2; ++ntl) {
      const int scol = w * 32 + ntl * 16 + l15;
      short8 bh8, bl8;
#pragma unroll
      for (int j = 0; j < 8; ++j) {
        short h, l; bsplit(Bs[g4 * 8 + j][scol] * dte[j], h, l);
        bh8[j] = h; bl8[j] = l;
      }
#pragma unroll
      for (int mt = 0; mt < 4; ++mt) {
        acc[mt][ntl] = __builtin_amdgcn_mfma_f32_16x16x32_bf16(xh[mt], bh8, acc[mt][ntl], 0, 0, 0);
        acc[mt][ntl] = __builtin_amdgcn_mfma_f32_16x16x32_bf16(xh[mt], bl8, acc[mt][ntl], 0, 0, 0);
        acc[mt][ntl] = __builtin_amdgcn_mfma_f32_16x16x32_bf16(xl[mt], bh8, acc[mt][ntl], 0, 0, 0);
      }
    }
    __syncthreads();
  }
  // D layout: col = lane&15 (s), row = (lane>>4)*4 + r (d). store hT[d][s]
#pragma unroll
  for (int mt = 0; mt < 4; ++mt)
#pragma unroll
    for (int ntl = 0; ntl < 2; ++ntl)
#pragma unroll
      for (int r = 0; r < 4; ++r)
        hout[(size_t)(mt * 16 + g4 * 4 + r) * DS + w * 32 + ntl * 16 + l15] = acc[mt][ntl][r];
}

// ---------------- Phase 2: scan over chunks (hbuf is transposed [d][s]; h0/hfinal are [s][d]) ----------------
__global__ __launch_bounds__(256) void p2_scan(
    const float* __restrict__ h0, const float* __restrict__ dtot,
    float* __restrict__ hbuf, float* __restrict__ hfinal)
{
  int g = blockIdx.x * 256 + threadIdx.x;   // 0 .. 524287
  int bh = g >> 13;
  int e  = g & 8191;                        // e = d*128 + s  (hbuf layout)
  int d  = e >> 7, sidx = e & 127;
  size_t h0i = (size_t)bh * 8192 + sidx * 64 + d;
  float s = h0[h0i];
  const float* dt = dtot + bh * NC;
  float* p = hbuf + (size_t)bh * NC * 8192 + e;
#pragma unroll 1
  for (int cc = 0; cc < NC; ++cc) {
    float hc = p[(size_t)cc * 8192];
    p[(size_t)cc * 8192] = s;               // state at START of chunk cc
    s = fmaf(dt[cc], s, hc);
  }
  hfinal[h0i] = s;
}

// ---------------- Phase 3: Y = (L .* C B^T) X + diag(exp(csum)) C h   (MFMA bf16x3) ----------------
__global__ __launch_bounds__(256, 3) void p3_y(
    const float* __restrict__ A, const float* __restrict__ X,
    const float* __restrict__ B, const float* __restrict__ C,
    const float* __restrict__ hbuf, float* __restrict__ Y)
{
  __shared__ float csum[CS];
  __shared__ __align__(16) char smem[51200];

  // phase BE layout (per k-tile): C,B as [128][40] bf16 hi/lo, hT as [64][40]
  short* Chi = (short*)smem;
  short* Clo = Chi + 5120;
  short* Bhi = Clo + 5120;
  short* Blo = Bhi + 5120;
  short* Hhi = Blo + 5120;
  short* Hlo = Hhi + 2560;
  // phase D layout (per j-tile): T as [128][40] hi/lo, X fp32 [32][65]
  short* Thi = (short*)smem;
  short* Tlo = Thi + 5120;
  float* Xs  = (float*)(smem + 20480);

  const int blk = blockIdx.x;
  const int bh  = blk >> 5;
  const int c   = blk & 31;
  const int tid = threadIdx.x;
  const int lane = tid & 63, w = tid >> 6;
  const int g4 = lane >> 4, l15 = lane & 15;
  const int w32 = w * 32;

  const float* Ac = A + bh * SEQ + c * CS;
  const float* Xc = X + (size_t)(bh * SEQ + c * CS) * DH;
  const float* Bc = B + (size_t)(bh * SEQ + c * CS) * DS;
  const float* Cc = C + (size_t)(bh * SEQ + c * CS) * DS;
  const float* hst = hbuf + (size_t)blk * DS * DH;   // [DH][DS] transposed
  float* Yc = Y + (size_t)(bh * SEQ + c * CS) * DH;

  if (tid < CS) csum[tid] = Ac[tid];
  __syncthreads();
  for (int off = 1; off < CS; off <<= 1) {
    float v = 0.f;
    if (tid < CS) { v = csum[tid]; if (tid >= off) v += csum[tid - off]; }
    __syncthreads();
    if (tid < CS) csum[tid] = v;
    __syncthreads();
  }

  float csI[2][4];
#pragma unroll
  for (int mt = 0; mt < 2; ++mt)
#pragma unroll
    for (int r = 0; r < 4; ++r) csI[mt][r] = csum[w32 + mt * 16 + g4 * 4 + r];

  f32x4 accCB[2][8];   // full 128x128 CB, this wave's 32 rows
  f32x4 accY[2][4];    // accumulates C*h, then decayed, then += T*X
#pragma unroll
  for (int mt = 0; mt < 2; ++mt) {
#pragma unroll
    for (int n = 0; n < 8; ++n) accCB[mt][n] = (f32x4){0.f,0.f,0.f,0.f};
#pragma unroll
    for (int n = 0; n < 4; ++n) accY[mt][n] = (f32x4){0.f,0.f,0.f,0.f};
  }

  // ---- fused K-loop: CB = C*B^T  and  Ch = C*h (K = state dim s) ----
  for (int kt = 0; kt < 4; ++kt) {
    const int k0 = kt * 32;
#pragma unroll
    for (int m = 0; m < 4; ++m) {
      int q = m * 256 + tid; int r = q >> 3, c4 = q & 7;
      short4v hv, lv;
      float4 v = *(const float4*)(Cc + (size_t)r * DS + k0 + c4 * 4);
      split4(v, hv, lv);
      *(short4v*)(Chi + r * 40 + c4 * 4) = hv;
      *(short4v*)(Clo + r * 40 + c4 * 4) = lv;
      float4 vb = *(const float4*)(Bc + (size_t)r * DS + k0 + c4 * 4);
      split4(vb, hv, lv);
      *(short4v*)(Bhi + r * 40 + c4 * 4) = hv;
      *(short4v*)(Blo + r * 40 + c4 * 4) = lv;
    }
#pragma unroll
    for (int m = 0; m < 2; ++m) {
      int q = m * 256 + tid; int r = q >> 3, c4 = q & 7;
      short4v hv, lv;
      float4 v = *(const float4*)(hst + (size_t)r * DS + k0 + c4 * 4);
      split4(v, hv, lv);
      *(short4v*)(Hhi + r * 40 + c4 * 4) = hv;
      *(short4v*)(Hlo + r * 40 + c4 * 4) = lv;
    }
    __syncthreads();

    short8 ah[2], al[2];
#pragma unroll
    for (int mt = 0; mt < 2; ++mt) {
      ah[mt] = *(const short8*)(Chi + (w32 + mt * 16 + l15) * 40 + g4 * 8);
      al[mt] = *(const short8*)(Clo + (w32 + mt * 16 + l15) * 40 + g4 * 8);
    }
#pragma unroll
    for (int nt = 0; nt < 8; ++nt) {
      short8 bh8 = *(const short8*)(Bhi + (nt * 16 + l15) * 40 + g4 * 8);
      short8 bl8 = *(const short8*)(Blo + (nt * 16 + l15) * 40 + g4 * 8);
#pragma unroll
      for (int mt = 0; mt < 2; ++mt) {
        accCB[mt][nt] = __builtin_amdgcn_mfma_f32_16x16x32_bf16(ah[mt], bh8, accCB[mt][nt], 0, 0, 0);
        accCB[mt][nt] = __builtin_amdgcn_mfma_f32_16x16x32_bf16(ah[mt], bl8, accCB[mt][nt], 0, 0, 0);
        accCB[mt][nt] = __builtin_amdgcn_mfma_f32_16x16x32_bf16(al[mt], bh8, accCB[mt][nt], 0, 0, 0);
      }
    }
#pragma unroll
    for (int nd = 0; nd < 4; ++nd) {
      short8 hh = *(const short8*)(Hhi + (nd * 16 + l15) * 40 + g4 * 8);
      short8 hl = *(const short8*)(Hlo + (nd * 16 + l15) * 40 + g4 * 8);
#pragma unroll
      for (int mt = 0; mt < 2; ++mt) {
        accY[mt][nd] = __builtin_amdgcn_mfma_f32_16x16x32_bf16(ah[mt], hh, accY[mt][nd], 0, 0, 0);
        accY[mt][nd] = __builtin_amdgcn_mfma_f32_16x16x32_bf16(ah[mt], hl, accY[mt][nd], 0, 0, 0);
        accY[mt][nd] = __builtin_amdgcn_mfma_f32_16x16x32_bf16(al[mt], hh, accY[mt][nd], 0, 0, 0);
      }
    }
    __syncthreads();
  }

  // Y_inter scale: diag(exp(csum)) applied on output rows
#pragma unroll
  for (int mt = 0; mt < 2; ++mt)
#pragma unroll
    for (int r = 0; r < 4; ++r) {
      float ei = __expf(csI[mt][r]);
#pragma unroll
      for (int nd = 0; nd < 4; ++nd) accY[mt][nd][r] *= ei;
    }

  // ---- intra: per 32-col slab of T = mask(L .* CB): regs -> LDS -> MFMA with X ----
#pragma unroll
  for (int jt = 0; jt < 4; ++jt) {
#pragma unroll
    for (int ntb = 0; ntb < 2; ++ntb) {
      const int nt = jt * 2 + ntb;
      const int jj = ntb * 16 + l15;
      const int j  = jt * 32 + jj;
      const float csj = csum[j];
#pragma unroll
      for (int mt = 0; mt < 2; ++mt)
#pragma unroll
        for (int r = 0; r < 4; ++r) {
          int i = w32 + mt * 16 + g4 * 4 + r;
          float v = (i >= j) ? accCB[mt][nt][r] * __expf(csI[mt][r] - csj) : 0.f;
          short h, l; bsplit(v, h, l);
          Thi[i * 40 + jj] = h;
          Tlo[i * 40 + jj] = l;
        }
    }
#pragma unroll
    for (int m = 0; m < 2; ++m) {
      int q = m * 256 + tid; int r = q >> 4, c4 = q & 15;
      float4 v = *(const float4*)(Xc + (size_t)(jt * 32 + r) * DH + c4 * 4);
      Xs[r * 65 + c4*4+0] = v.x; Xs[r * 65 + c4*4+1] = v.y;
      Xs[r * 65 + c4*4+2] = v.z; Xs[r * 65 + c4*4+3] = v.w;
    }
    __syncthreads();

    short8 th[2], tl[2];
#pragma unroll
    for (int mt = 0; mt < 2; ++mt) {
      th[mt] = *(const short8*)(Thi + (w32 + mt * 16 + l15) * 40 + g4 * 8);
      tl[mt] = *(const short8*)(Tlo + (w32 + mt * 16 + l15) * 40 + g4 * 8);
    }
#pragma unroll
    for (int nd = 0; nd < 4; ++nd) {
      short8 xh8, xl8;
#pragma unroll
      for (int jq = 0; jq < 8; ++jq) {
        short h, l; bsplit(Xs[(g4 * 8 + jq) * 65 + nd * 16 + l15], h, l);
        xh8[jq] = h; xl8[jq] = l;
      }
#pragma unroll
      for (int mt = 0; mt < 2; ++mt) {
        accY[mt][nd] = __builtin_amdgcn_mfma_f32_16x16x32_bf16(th[mt], xh8, accY[mt][nd], 0, 0, 0);
        accY[mt][nd] = __builtin_amdgcn_mfma_f32_16x16x32_bf16(th[mt], xl8, accY[mt][nd], 0, 0, 0);
        accY[mt][nd] = __builtin_amdgcn_mfma_f32_16x16x32_bf16(tl[mt], xh8, accY[mt][nd], 0, 0, 0);
      }
    }
    __syncthreads();
  }

#pragma unroll
  for (int mt = 0; mt < 2; ++mt)
#pragma unroll
    for (int nd = 0; nd < 4; ++nd)
#pragma unroll
      for (int r = 0; r < 4; ++r)
        Yc[(size_t)(w32 + mt * 16 + g4 * 4 + r) * DH + nd * 16 + l15] = accY[mt][nd][r];
}

extern "C" void kernel_launch(void* const* d_in, const int* in_sizes, int n_in,
                              void* d_out, int out_size, void* d_ws, size_t ws_size,
                              hipStream_t stream)
{
  const float* X  = (const float*)d_in[0];
  const float* A  = (const float*)d_in[1];
  const float* B  = (const float*)d_in[2];
  const float* C  = (const float*)d_in[3];
  const float* h0 = (const float*)d_in[4];

  float* Y      = (float*)d_out;
  float* hfinal = Y + (size_t)NBH * SEQ * DH;

  float* hbuf = (float*)d_ws;                          // 64*32*8192 floats (transposed [d][s] per chunk)
  float* dtot = hbuf + (size_t)NBH * NC * DS * DH;     // 2048 floats

  dim3 blk(256);
  p1_hcontrib<<<dim3(NBH * NC), blk, 0, stream>>>(A, X, B, hbuf, dtot);
  p2_scan<<<dim3((NBH * DS * DH) / 256), blk, 0, stream>>>(h0, dtot, hbuf, hfinal);
  p3_y<<<dim3(NBH * NC), blk, 0, stream>>>(A, X, B, C, hbuf, Y);
}